// Round 8
// baseline (196.392 us; speedup 1.0000x reference)
//
#include <hip/hip_runtime.h>
#include <math.h>

// DotProductAttention: B=16, Q=2048, K=2048, D=128, fp32 in/out.
// Query-axis masking only: rows q >= valid_lens[b] -> uniform softmax -> mean(V).
//
// R17: 2 Q-TILES PER WAVE (halve LDS reads per output). Established by
// R10-R16: both MFMA operands must come from LDS (R12/R16: any global->MFMA
// operand path convoys on vmcnt and loses 2-3x); R11's structure is healthy
// and its binding resource is the LDS read pipe (4 waves x 32 KB re-read per
// slice; ~12cyc/ds_read_b128 matches measured ~2000-2500 cyc/slice; R15:
// HBM/L2-locality/balance all non-binding). Lever: each wave owns 64 q-rows;
// one kf read feeds T0+T1 MFMAs, one vf pair feeds O[dt]+O[4+dt] -> LDS
// bytes per q*key HALVE, MFMA:ds_read doubles. VGPR ~245 fits (256,2) cap
// of 256 (R13/R14 failures were caps far below liveness). SEG=8 keeps ~576
// active blocks; balanced grid (x=qt prefix). All fragment/slot/swizzle
// formulas verbatim from R5/R8-verified code. combine<8> closes softmax.
//
// ws: sumV 8K | Kh 8.39M | Vt 8.39M | Qh 8.39M | Po 8x8.39M | Lb 8x128K
//     (~93.3 MB; SEG=4/2 fallbacks).

#define Bn 16
#define Qn 2048
#define Kn 2048
#define Dn 128
#define SCALE 0.08838834764831845f  // 1/sqrt(128)

typedef _Float16 f16;
typedef _Float16 f16x8_t __attribute__((ext_vector_type(8)));
typedef float f32x16_t __attribute__((ext_vector_type(16)));

typedef __attribute__((address_space(1))) const unsigned int glb_u32;
typedef __attribute__((address_space(3))) unsigned int lds_u32;

__device__ __forceinline__ void g2l16(const void* g, void* l) {
  __builtin_amdgcn_global_load_lds((glb_u32*)g, (lds_u32*)l, 16, 0, 0);
}

// ---------------- prep: K->f16 swizzled rows, V->Vt 64-key tiles, Q->f16,
// colsum. grid (32, 4, 16) block (32,8).   [verbatim R11/R15, HW-verified]
// Kh key-row k (256B): granule G=d>>3 at slot (G&8)|((G&7)^(k&7))
// Vt tile [b][k/64][d][kk] 16KB, G=kk>>3 at G^(d&7)
// Qh: plain row-major f16.

__global__ void __launch_bounds__(256) prep_kernel(
    const float* __restrict__ Qg, const float* __restrict__ Kg,
    const float* __restrict__ Vg, f16* __restrict__ Qh, f16* __restrict__ Kh,
    f16* __restrict__ Vt, float* __restrict__ sv) {
  __shared__ float ps[8][32];
  const int b = blockIdx.z;
  const int x = threadIdx.x, y = threadIdx.y;

  // K and Q: 16 rows per block, one granule (8 d) per thread
  {
    const int lb = (b * 4 + blockIdx.y) * 32 + blockIdx.x;  // 0..2047
    const int t = y * 32 + x;
    const size_t key = (size_t)lb * 16 + (t >> 4);  // global (b*2048+k)
    const int G = t & 15;
    const float* kp = Kg + (key << 7) + G * 8;
    float4 f0 = *(const float4*)kp;
    float4 f1 = *(const float4*)(kp + 4);
    f16x8_t o;
    o[0] = (f16)f0.x; o[1] = (f16)f0.y; o[2] = (f16)f0.z; o[3] = (f16)f0.w;
    o[4] = (f16)f1.x; o[5] = (f16)f1.y; o[6] = (f16)f1.z; o[7] = (f16)f1.w;
    const int gs = (G & 8) | ((G & 7) ^ ((int)key & 7));
    *(f16x8_t*)(Kh + (key << 7) + (gs << 3)) = o;

    const float* qp = Qg + (key << 7) + G * 8;
    float4 q0 = *(const float4*)qp;
    float4 q1 = *(const float4*)(qp + 4);
    f16x8_t oq;
    oq[0] = (f16)q0.x; oq[1] = (f16)q0.y; oq[2] = (f16)q0.z; oq[3] = (f16)q0.w;
    oq[4] = (f16)q1.x; oq[5] = (f16)q1.y; oq[6] = (f16)q1.z; oq[7] = (f16)q1.w;
    *(f16x8_t*)(Qh + (key << 7) + G * 8) = oq;  // plain row-major
  }

  // V: 64 keys x 32 d per block; thread owns one Vt granule in-register
  const int k0 = blockIdx.x * 64, d0 = blockIdx.y * 32;
  const int d = d0 + x;
  const float* vp = Vg + ((size_t)b * Kn + k0 + y * 8) * Dn + d;
  float s = 0.f;
  f16x8_t gr;
#pragma unroll
  for (int j = 0; j < 8; j++) {
    float v = vp[(size_t)j * Dn];
    s += v;
    gr[j] = (f16)v;
  }
  {
    const int kb = k0 >> 6;
    const int G = y;  // kk granule 0..7
    const int gs = G ^ (d & 7);
    *(f16x8_t*)(Vt + (((size_t)(b * (Kn / 64) + kb) * 128 + d) << 6) + (gs << 3)) = gr;
  }

  // column sums for the masked fast path
  ps[y][x] = s;
  __syncthreads();
  if (y == 0) {
    float tot = 0.f;
#pragma unroll
    for (int j = 0; j < 8; j++) tot += ps[j][x];
    atomicAdd(&sv[b * Dn + d0 + x], tot);
  }
}

// valid_lens may be stored as int32 or int64. Sniff: odd words all zero -> 64.
__device__ __forceinline__ int load_vl(const int* __restrict__ vlp, int b) {
  bool is64 = true;
#pragma unroll
  for (int i = 1; i < 16; i += 2) is64 = is64 && (vlp[i] == 0);
  return is64 ? vlp[2 * b] : vlp[b];
}

// ---------------- flashW<SEG>: 64 q-rows per wave, K+V LDS dbuf (R11 slice
// loop verbatim). grid (8, SEG, Bn) block 256 (4 waves -> 256 q-rows/block).
// Per 64-key slice: 1 kf read -> 2 MFMAs (T0,T1); 1 vf pair -> 4 MFMAs.
// Writes unnormalized f16 O-partials + l-partials; combine<SEG> finishes.

template <int SEG>
__global__ void __launch_bounds__(256, 2) flashW(
    const f16* __restrict__ Qh, const f16* __restrict__ Kh,
    const f16* __restrict__ Vt, const int* __restrict__ vlp,
    f16* __restrict__ Po, float* __restrict__ Lb) {
  const int qt = blockIdx.x;   // 256-row q-tile
  const int seg = blockIdx.y;
  const int b = blockIdx.z;
  const int q0 = qt << 8;
  const int vl = load_vl(vlp, b);
  if (q0 >= vl) return;  // fully-masked tile: combine writes mean(V)

  __shared__ __align__(16) f16 Ks[2][64 * 128];  // 2 x 16 KB
  __shared__ __align__(16) f16 Vs[2][128 * 64];  // 2 x 16 KB

  const int tid = threadIdx.x;
  const int wave = tid >> 6, lane = tid & 63;
  const int H = lane >> 5, l5 = lane & 31;
  const int qbase = q0 + wave * 64;  // this wave's 64 q-rows
  const bool wact = qbase < vl;      // masked wave: stage+barrier only
  const int qA = qbase + l5;         // half0 row for this lane
  const int qB = qbase + 32 + l5;    // half1 row
  const float scA = (qA >= vl) ? 0.f : SCALE;  // masked row: p=1
  const float scB = (qB >= vl) ? 0.f : SCALE;

  // pi = swap bits 2<->3: A-row slot l5 holds physical key pi(l5) [verified]
  const int krow = (l5 & 0x13) | ((l5 & 4) << 1) | ((l5 & 8) >> 1);
  const int krow7 = krow & 7;

  // Q fragments for both halves (B-operand of S^T), loaded once [verbatim]
  f16x8_t qf0[8], qf1[8];
  if (wact) {
    const f16* qpA = Qh + ((size_t)b * Qn + qA) * Dn + 8 * H;
    const f16* qpB = Qh + ((size_t)b * Qn + qB) * Dn + 8 * H;
#pragma unroll
    for (int s = 0; s < 8; s++) {
      qf0[s] = *(const f16x8_t*)(qpA + 16 * s);
      qf1[s] = *(const f16x8_t*)(qpB + 16 * s);
    }
  }

  f32x16_t O[8];
#pragma unroll
  for (int i = 0; i < 8; i++) O[i] = (f32x16_t)(0.f);
  float lA = 0.f, lB = 0.f;

  // segment base: keys seg*(Kn/SEG) .. (R11 verbatim addressing)
  const char* KgT = (const char*)Kh + (((size_t)b * Kn + seg * (Kn / SEG)) << 8);
  const char* VgT =
      (const char*)Vt + ((size_t)(b * (Kn / 64) + seg * ((Kn / SEG) / 64)) << 14);
  const int NSL = (Kn / SEG) / 64;  // 64-key slices per block

  // stage slice 0 into buf 0
  {
    const char* kg = KgT + wave * 4096 + lane * 16;
    const char* vg = VgT + wave * 4096 + lane * 16;
    f16* kl = Ks[0] + wave * 2048;
    f16* vli = Vs[0] + wave * 2048;
#pragma unroll
    for (int i = 0; i < 4; i++) {
      g2l16(kg + i * 1024, kl + i * 512);
      g2l16(vg + i * 1024, vli + i * 512);
    }
  }
  __syncthreads();

  int buf = 0;
  for (int sl = 0; sl < NSL; sl++) {
    // issue next slice's DMA first -> overlaps with compute below
    if (sl < NSL - 1) {
      const char* kg = KgT + (size_t)(sl + 1) * 16384 + wave * 4096 + lane * 16;
      const char* vg = VgT + (size_t)(sl + 1) * 16384 + wave * 4096 + lane * 16;
      f16* kl = Ks[buf ^ 1] + wave * 2048;
      f16* vli = Vs[buf ^ 1] + wave * 2048;
#pragma unroll
      for (int i = 0; i < 4; i++) {
        g2l16(kg + i * 1024, kl + i * 512);
        g2l16(vg + i * 1024, vli + i * 512);
      }
    }

    if (wact) {
#pragma unroll
      for (int sub = 0; sub < 2; sub++) {
        // S^T = K.Q^T over 32 keys, BOTH q-halves share each kf read
        f32x16_t T0 = (f32x16_t)(0.f);
        f32x16_t T1 = (f32x16_t)(0.f);
        const f16* krp = Ks[buf] + ((sub * 32 + krow) << 7);
#pragma unroll
        for (int s = 0; s < 8; s++) {
          const int G = 2 * s + H;
          const int gs = (G & 8) | ((G & 7) ^ krow7);
          f16x8_t kf = *(const f16x8_t*)(krp + (gs << 3));
          T0 = __builtin_amdgcn_mfma_f32_32x32x16_f16(kf, qf0[s], T0, 0, 0, 0);
          T1 = __builtin_amdgcn_mfma_f32_32x32x16_f16(kf, qf1[s], T1, 0, 0, 0);
        }

        // p = exp(s*sc) for both halves; C-regs are the PV A-fragment
        f16x8_t pA0, pA1, pB0, pB1;
        float lsA = 0.f, lsB = 0.f;
#pragma unroll
        for (int r = 0; r < 8; r++) {
          float pa = __expf(T0[r] * scA);
          float pb = __expf(T1[r] * scB);
          lsA += pa; lsB += pb;
          pA0[r] = (f16)pa; pB0[r] = (f16)pb;
        }
#pragma unroll
        for (int r = 8; r < 16; r++) {
          float pa = __expf(T0[r] * scA);
          float pb = __expf(T1[r] * scB);
          lsA += pa; lsB += pb;
          pA1[r - 8] = (f16)pa; pB1[r - 8] = (f16)pb;
        }
        lA += lsA; lB += lsB;

        // O += P.V : one vf pair feeds 4 MFMAs (both halves)  [verbatim swz]
#pragma unroll
        for (int dt = 0; dt < 4; dt++) {
          const f16* vrp = Vs[buf] + ((dt * 32 + l5) << 6);
          const int G0 = sub * 4 + H, G1 = sub * 4 + 2 + H;
          const int gs0 = G0 ^ (l5 & 7);
          const int gs1 = G1 ^ (l5 & 7);
          f16x8_t vf0 = *(const f16x8_t*)(vrp + (gs0 << 3));
          f16x8_t vf1 = *(const f16x8_t*)(vrp + (gs1 << 3));
          O[dt] = __builtin_amdgcn_mfma_f32_32x32x16_f16(pA0, vf0, O[dt], 0, 0, 0);
          O[dt] = __builtin_amdgcn_mfma_f32_32x32x16_f16(pA1, vf1, O[dt], 0, 0, 0);
          O[4 + dt] =
              __builtin_amdgcn_mfma_f32_32x32x16_f16(pB0, vf0, O[4 + dt], 0, 0, 0);
          O[4 + dt] =
              __builtin_amdgcn_mfma_f32_32x32x16_f16(pB1, vf1, O[4 + dt], 0, 0, 0);
        }
      }
    }
    __syncthreads();  // next-slice DMA complete + buf safe to overwrite
    buf ^= 1;
  }

  if (!wact) return;

  // epilogue: unnormalized partials for both halves  [verbatim pattern]
  float llA = lA + __shfl_xor(lA, 32);
  float llB = lB + __shfl_xor(lB, 32);
  if (lane < 32) {
    Lb[(size_t)(seg * Bn + b) * Qn + qbase + l5] = llA;
    Lb[(size_t)(seg * Bn + b) * Qn + qbase + 32 + l5] = llB;
  }

  f16* po = Po + ((size_t)(seg * Bn + b) * Qn + qbase) * Dn;
#pragma unroll
  for (int dt = 0; dt < 4; dt++) {
#pragma unroll
    for (int r = 0; r < 16; r++) {
      const int qrow = (r & 3) + 8 * (r >> 2) + 4 * H;  // PV C-layout row
      po[(size_t)qrow * Dn + dt * 32 + l5] = (f16)O[dt][r];
      po[(size_t)(32 + qrow) * Dn + dt * 32 + l5] = (f16)O[4 + dt][r];
    }
  }
}

// ---------------- combine: out = sum_s O_s / sum_s l_s; masked rows = mean(V)
// grid (32, 16) block 256; 64 q-rows per block, 8 d per thread.  [verbatim]

template <int S>
__global__ void __launch_bounds__(256) combine_kernel(
    const f16* __restrict__ Po, const float* __restrict__ Lb,
    const float* __restrict__ sv, const int* __restrict__ vlp,
    float* __restrict__ Out) {
  const int b = blockIdx.y, q0 = blockIdx.x * 64;
  const int vl = load_vl(vlp, b);
  const int tid = threadIdx.x;

  __shared__ float linv[64];
  if (tid < 64) {
    float s = 0.f;
#pragma unroll
    for (int sg = 0; sg < S; sg++) s += Lb[(size_t)(sg * Bn + b) * Qn + q0 + tid];
    linv[tid] = 1.0f / s;
  }
  __syncthreads();

  const int row16 = tid >> 4;     // 0..15
  const int d8 = (tid & 15) * 8;  // 0..120
  const float invK = 1.0f / (float)Kn;
  float mv[8];
#pragma unroll
  for (int j = 0; j < 8; j++) mv[j] = sv[b * Dn + d8 + j] * invK;

#pragma unroll
  for (int pass = 0; pass < 4; pass++) {
    const int row = pass * 16 + row16;
    const int q = q0 + row;
    float acc[8];
    if (q >= vl) {
#pragma unroll
      for (int j = 0; j < 8; j++) acc[j] = mv[j];
    } else {
#pragma unroll
      for (int j = 0; j < 8; j++) acc[j] = 0.f;
#pragma unroll
      for (int sg = 0; sg < S; sg++) {
        f16x8_t v = *(const f16x8_t*)(Po + ((size_t)(sg * Bn + b) * Qn + q) * Dn + d8);
#pragma unroll
        for (int j = 0; j < 8; j++) acc[j] += (float)v[j];
      }
      const float li = linv[row];
#pragma unroll
      for (int j = 0; j < 8; j++) acc[j] *= li;
    }
    float4 o0 = make_float4(acc[0], acc[1], acc[2], acc[3]);
    float4 o1 = make_float4(acc[4], acc[5], acc[6], acc[7]);
    float* op = Out + ((size_t)b * Qn + q) * Dn + d8;
    *(float4*)op = o0;
    *(float4*)(op + 4) = o1;
  }
}

// ---------------- launch ----------------

extern "C" void kernel_launch(void* const* d_in, const int* in_sizes, int n_in,
                              void* d_out, int out_size, void* d_ws, size_t ws_size,
                              hipStream_t stream) {
  const float* Qg = (const float*)d_in[0];
  const float* Kg = (const float*)d_in[1];
  const float* Vg = (const float*)d_in[2];
  const int* vl = (const int*)d_in[3];
  float* Out = (float*)d_out;

  char* ws = (char*)d_ws;
  const size_t kv = (size_t)Bn * Kn * Dn * 2;  // 8.39 MB each
  float* sumV = (float*)ws;                    // 8 KB
  f16* Kh = (f16*)(ws + 8192);
  f16* Vt = (f16*)(ws + 8192 + kv);
  f16* Qh = (f16*)(ws + 8192 + 2 * kv);

  const size_t plane = (size_t)Bn * Qn * Dn * 2;  // 8.39 MB
  const size_t lplane = (size_t)Bn * Qn * 4;      // 128 KB
  const size_t base = 8192 + 3 * kv;              // ~25.2 MB
  f16* Po = (f16*)(ws + base);

  hipMemsetAsync(sumV, 0, Bn * Dn * sizeof(float), stream);

  prep_kernel<<<dim3(32, 4, Bn), dim3(32, 8), 0, stream>>>(
      Qg, Kg, Vg, Qh, Kh, Vt, sumV);

  // grid (x=qt, y=seg, z=b): active q-prefix round-robins across XCDs/CUs
  if (ws_size >= base + 8 * (plane + lplane)) {
    float* Lb = (float*)(ws + base + 8 * plane);
    flashW<8><<<dim3(8, 8, Bn), 256, 0, stream>>>(Qh, Kh, Vt, vl, Po, Lb);
    combine_kernel<8><<<dim3(Qn / 64, Bn), 256, 0, stream>>>(Po, Lb, sumV, vl, Out);
  } else if (ws_size >= base + 4 * (plane + lplane)) {
    float* Lb = (float*)(ws + base + 4 * plane);
    flashW<4><<<dim3(8, 4, Bn), 256, 0, stream>>>(Qh, Kh, Vt, vl, Po, Lb);
    combine_kernel<4><<<dim3(Qn / 64, Bn), 256, 0, stream>>>(Po, Lb, sumV, vl, Out);
  } else {
    float* Lb = (float*)(ws + base + 2 * plane);
    flashW<2><<<dim3(8, 2, Bn), 256, 0, stream>>>(Qh, Kh, Vt, vl, Po, Lb);
    combine_kernel<2><<<dim3(Qn / 64, Bn), 256, 0, stream>>>(Po, Lb, sumV, vl, Out);
  }
}

// Round 9
// 144.742 us; speedup vs baseline: 1.3568x; 1.3568x over previous
//
#include <hip/hip_runtime.h>
#include <math.h>

// DotProductAttention: B=16, Q=2048, K=2048, D=128, fp32 in/out.
// Query-axis masking only: rows q >= valid_lens[b] -> uniform softmax -> mean(V).
//
// R18: COUNTED-VMCNT SYNC (T4), single variable vs R15. Evidence: R11/R15
// per-slice wall ~5.5-6.5us-equiv vs ~1.2us LDS work + ~0.5us DMA service;
// all pipes <15%. R15's __syncthreads drains vmcnt(0) each slice -> prefetch
// cover = one compute phase only; 64 concurrent 1KB DMAs/CU queue longer.
// Fix (m201 pattern): issue next slice, then s_waitcnt vmcnt(8) (last iter's
// loads only; new 8 stay in flight ACROSS the barrier) + raw s_barrier +
// sched_barrier(0); after compute: lgkmcnt(0) + raw s_barrier (no vmcnt
// drain). Last iter waits vmcnt(0). Everything else byte-identical to R15
// (proven passing): register regime (256,2)/VGPR=100, 32 q-rows/wave,
// 64KB K+V LDS dbuf, balanced grid (x=qt,y=seg,z=b), verbatim swizzles.
// Failed-regime rules: no launch_bounds occupancy floors (R13/R14/R17
// VGPR-clamp spills); no global->MFMA operands (R12/R16 vmcnt convoy).
//
// ws: sumV 8K | Kh 8.39M | Vt 8.39M | Qh 8.39M | Po 4x8.39M | Lb 4x128K.

#define Bn 16
#define Qn 2048
#define Kn 2048
#define Dn 128
#define SCALE 0.08838834764831845f  // 1/sqrt(128)

typedef _Float16 f16;
typedef _Float16 f16x8_t __attribute__((ext_vector_type(8)));
typedef float f32x16_t __attribute__((ext_vector_type(16)));

typedef __attribute__((address_space(1))) const unsigned int glb_u32;
typedef __attribute__((address_space(3))) unsigned int lds_u32;

__device__ __forceinline__ void g2l16(const void* g, void* l) {
  __builtin_amdgcn_global_load_lds((glb_u32*)g, (lds_u32*)l, 16, 0, 0);
}

// ---------------- prep: K->f16 swizzled rows, V->Vt 64-key tiles, Q->f16,
// colsum. grid (32, 4, 16) block (32,8).   [verbatim R11/R15, HW-verified]
// Kh key-row k (256B): granule G=d>>3 at slot (G&8)|((G&7)^(k&7))
// Vt tile [b][k/64][d][kk] 16KB, G=kk>>3 at G^(d&7)
// Qh: plain row-major f16.

__global__ void __launch_bounds__(256) prep_kernel(
    const float* __restrict__ Qg, const float* __restrict__ Kg,
    const float* __restrict__ Vg, f16* __restrict__ Qh, f16* __restrict__ Kh,
    f16* __restrict__ Vt, float* __restrict__ sv) {
  __shared__ float ps[8][32];
  const int b = blockIdx.z;
  const int x = threadIdx.x, y = threadIdx.y;

  // K and Q: 16 rows per block, one granule (8 d) per thread
  {
    const int lb = (b * 4 + blockIdx.y) * 32 + blockIdx.x;  // 0..2047
    const int t = y * 32 + x;
    const size_t key = (size_t)lb * 16 + (t >> 4);  // global (b*2048+k)
    const int G = t & 15;
    const float* kp = Kg + (key << 7) + G * 8;
    float4 f0 = *(const float4*)kp;
    float4 f1 = *(const float4*)(kp + 4);
    f16x8_t o;
    o[0] = (f16)f0.x; o[1] = (f16)f0.y; o[2] = (f16)f0.z; o[3] = (f16)f0.w;
    o[4] = (f16)f1.x; o[5] = (f16)f1.y; o[6] = (f16)f1.z; o[7] = (f16)f1.w;
    const int gs = (G & 8) | ((G & 7) ^ ((int)key & 7));
    *(f16x8_t*)(Kh + (key << 7) + (gs << 3)) = o;

    const float* qp = Qg + (key << 7) + G * 8;
    float4 q0 = *(const float4*)qp;
    float4 q1 = *(const float4*)(qp + 4);
    f16x8_t oq;
    oq[0] = (f16)q0.x; oq[1] = (f16)q0.y; oq[2] = (f16)q0.z; oq[3] = (f16)q0.w;
    oq[4] = (f16)q1.x; oq[5] = (f16)q1.y; oq[6] = (f16)q1.z; oq[7] = (f16)q1.w;
    *(f16x8_t*)(Qh + (key << 7) + G * 8) = oq;  // plain row-major
  }

  // V: 64 keys x 32 d per block; thread owns one Vt granule in-register
  const int k0 = blockIdx.x * 64, d0 = blockIdx.y * 32;
  const int d = d0 + x;
  const float* vp = Vg + ((size_t)b * Kn + k0 + y * 8) * Dn + d;
  float s = 0.f;
  f16x8_t gr;
#pragma unroll
  for (int j = 0; j < 8; j++) {
    float v = vp[(size_t)j * Dn];
    s += v;
    gr[j] = (f16)v;
  }
  {
    const int kb = k0 >> 6;
    const int G = y;  // kk granule 0..7
    const int gs = G ^ (d & 7);
    *(f16x8_t*)(Vt + (((size_t)(b * (Kn / 64) + kb) * 128 + d) << 6) + (gs << 3)) = gr;
  }

  // column sums for the masked fast path
  ps[y][x] = s;
  __syncthreads();
  if (y == 0) {
    float tot = 0.f;
#pragma unroll
    for (int j = 0; j < 8; j++) tot += ps[j][x];
    atomicAdd(&sv[b * Dn + d0 + x], tot);
  }
}

// valid_lens may be stored as int32 or int64. Sniff: odd words all zero -> 64.
__device__ __forceinline__ int load_vl(const int* __restrict__ vlp, int b) {
  bool is64 = true;
#pragma unroll
  for (int i = 1; i < 16; i += 2) is64 = is64 && (vlp[i] == 0);
  return is64 ? vlp[2 * b] : vlp[b];
}

// ---------------- flash4: SEG=4 partial flash. grid (16, 4, Bn) block 256.
// Body = R15 (proven) except sync: counted vmcnt + raw barriers (T4).
// Per slice: {issue next 8 DMAs} -> vmcnt(8) [last iter's loads only] ->
// s_barrier -> sched_barrier -> compute -> lgkmcnt(0) -> s_barrier.

__global__ void __launch_bounds__(256, 2) flash4(
    const f16* __restrict__ Qh, const f16* __restrict__ Kh,
    const f16* __restrict__ Vt, const int* __restrict__ vlp,
    f16* __restrict__ Po, float* __restrict__ Lb) {
  const int qt = blockIdx.x;
  const int seg = blockIdx.y;
  const int b = blockIdx.z;
  const int q0 = qt << 7;
  const int vl = load_vl(vlp, b);
  if (q0 >= vl) return;  // fully-masked tile: combine writes mean(V)

  __shared__ __align__(16) f16 Ks[2][64 * 128];  // 2 x 16 KB
  __shared__ __align__(16) f16 Vs[2][128 * 64];  // 2 x 16 KB

  const int tid = threadIdx.x;
  const int wave = tid >> 6, lane = tid & 63;
  const int H = lane >> 5, l5 = lane & 31;
  const int qbase = q0 + wave * 32;
  const bool wact = qbase < vl;  // masked wave: stage+barrier only
  const int q_lane = qbase + l5;
  const float sc = (q_lane >= vl) ? 0.f : SCALE;  // masked row: p=1

  // pi = swap bits 2<->3: A-row slot l5 holds physical key pi(l5) [verified]
  const int krow = (l5 & 0x13) | ((l5 & 4) << 1) | ((l5 & 8) >> 1);
  const int krow7 = krow & 7;

  // Q fragment (B-operand of S^T), loaded once
  f16x8_t qf[8];
  if (wact) {
    const f16* qp = Qh + ((size_t)b * Qn + q_lane) * Dn + 8 * H;
#pragma unroll
    for (int s = 0; s < 8; s++) qf[s] = *(const f16x8_t*)(qp + 16 * s);
  }

  f32x16_t O[4];
#pragma unroll
  for (int i = 0; i < 4; i++) O[i] = (f32x16_t)(0.f);
  float l_lane = 0.f;

  // segment base: keys seg*512 .. +511
  const char* KgT = (const char*)Kh + (((size_t)b * Kn + seg * 512) << 8);
  const char* VgT = (const char*)Vt + ((size_t)(b * (Kn / 64) + seg * 8) << 14);

  // prologue: stage slice 0 into buf 0 (left in flight; iter 0 waits it)
  {
    const char* kg = KgT + wave * 4096 + lane * 16;
    const char* vg = VgT + wave * 4096 + lane * 16;
    f16* kl = Ks[0] + wave * 2048;
    f16* vli = Vs[0] + wave * 2048;
#pragma unroll
    for (int i = 0; i < 4; i++) {
      g2l16(kg + i * 1024, kl + i * 512);
      g2l16(vg + i * 1024, vli + i * 512);
    }
  }

  int buf = 0;
  for (int sl = 0; sl < 8; sl++) {
    // issue next slice's DMA first; it stays in flight across the barrier
    if (sl < 7) {
      const char* kg = KgT + (size_t)(sl + 1) * 16384 + wave * 4096 + lane * 16;
      const char* vg = VgT + (size_t)(sl + 1) * 16384 + wave * 4096 + lane * 16;
      f16* kl = Ks[buf ^ 1] + wave * 2048;
      f16* vli = Vs[buf ^ 1] + wave * 2048;
#pragma unroll
      for (int i = 0; i < 4; i++) {
        g2l16(kg + i * 1024, kl + i * 512);
        g2l16(vg + i * 1024, vli + i * 512);
      }
      // wait current slice's 8 loads (issued LAST iter; full-iter cover);
      // the 8 just-issued remain outstanding across the barrier (T4).
      asm volatile("s_waitcnt vmcnt(8)" ::: "memory");
    } else {
      asm volatile("s_waitcnt vmcnt(0)" ::: "memory");  // final slice: drain
    }
    __builtin_amdgcn_s_barrier();        // all waves: slice sl fully in LDS
    __builtin_amdgcn_sched_barrier(0);   // rule #18: pin LDS reads after wait

    if (wact) {
#pragma unroll
      for (int sub = 0; sub < 2; sub++) {
        // S^T = K.Q^T over keys (seg*512 + sl*64 + sub*32)..+31  [verbatim]
        f32x16_t T = (f32x16_t)(0.f);
        const f16* krp = Ks[buf] + ((sub * 32 + krow) << 7);
#pragma unroll
        for (int s = 0; s < 8; s++) {
          const int G = 2 * s + H;
          const int gs = (G & 8) | ((G & 7) ^ krow7);
          f16x8_t kf = *(const f16x8_t*)(krp + (gs << 3));
          T = __builtin_amdgcn_mfma_f32_32x32x16_f16(kf, qf[s], T, 0, 0, 0);
        }

        // p = exp(s*sc); C-regs are the PV A-fragment
        f16x8_t pf0, pf1;
        float ls = 0.f;
#pragma unroll
        for (int r = 0; r < 8; r++) {
          float p = __expf(T[r] * sc);
          ls += p;
          pf0[r] = (f16)p;
        }
#pragma unroll
        for (int r = 8; r < 16; r++) {
          float p = __expf(T[r] * sc);
          ls += p;
          pf1[r - 8] = (f16)p;
        }
        l_lane += ls;

        // O += P.V : B-frags from swizzled Vs (VT=64 layout)  [verbatim]
#pragma unroll
        for (int dt = 0; dt < 4; dt++) {
          const f16* vrp = Vs[buf] + ((dt * 32 + l5) << 6);
          const int G0 = sub * 4 + H, G1 = sub * 4 + 2 + H;
          const int gs0 = G0 ^ (l5 & 7);
          const int gs1 = G1 ^ (l5 & 7);
          f16x8_t vf0 = *(const f16x8_t*)(vrp + (gs0 << 3));
          f16x8_t vf1 = *(const f16x8_t*)(vrp + (gs1 << 3));
          O[dt] = __builtin_amdgcn_mfma_f32_32x32x16_f16(pf0, vf0, O[dt], 0, 0, 0);
          O[dt] = __builtin_amdgcn_mfma_f32_32x32x16_f16(pf1, vf1, O[dt], 0, 0, 0);
        }
      }
    }
    // reads of buf complete (lgkmcnt) before any wave's next-iter DMA can
    // overwrite it; NO vmcnt drain here — prefetch stays in flight.
    asm volatile("s_waitcnt lgkmcnt(0)" ::: "memory");
    __builtin_amdgcn_s_barrier();
    buf ^= 1;
  }

  if (!wact) return;

  // epilogue: unnormalized partials  [verbatim]
  float ll = l_lane + __shfl_xor(l_lane, 32);
  if (lane < 32) Lb[(size_t)(seg * Bn + b) * Qn + qbase + l5] = ll;

  f16* po = Po + ((size_t)(seg * Bn + b) * Qn + qbase) * Dn;
#pragma unroll
  for (int dt = 0; dt < 4; dt++) {
#pragma unroll
    for (int r = 0; r < 16; r++) {
      const int qrow = (r & 3) + 8 * (r >> 2) + 4 * H;  // PV C-layout row
      po[(size_t)qrow * Dn + dt * 32 + l5] = (f16)O[dt][r];
    }
  }
}

// ---------------- combine: out = sum_s O_s / sum_s l_s; masked rows = mean(V)
// grid (32, 16) block 256; 64 q-rows per block, 8 d per thread.  [verbatim]

template <int S>
__global__ void __launch_bounds__(256) combine_kernel(
    const f16* __restrict__ Po, const float* __restrict__ Lb,
    const float* __restrict__ sv, const int* __restrict__ vlp,
    float* __restrict__ Out) {
  const int b = blockIdx.y, q0 = blockIdx.x * 64;
  const int vl = load_vl(vlp, b);
  const int tid = threadIdx.x;

  __shared__ float linv[64];
  if (tid < 64) {
    float s = 0.f;
#pragma unroll
    for (int sg = 0; sg < S; sg++) s += Lb[(size_t)(sg * Bn + b) * Qn + q0 + tid];
    linv[tid] = 1.0f / s;
  }
  __syncthreads();

  const int row16 = tid >> 4;     // 0..15
  const int d8 = (tid & 15) * 8;  // 0..120
  const float invK = 1.0f / (float)Kn;
  float mv[8];
#pragma unroll
  for (int j = 0; j < 8; j++) mv[j] = sv[b * Dn + d8 + j] * invK;

#pragma unroll
  for (int pass = 0; pass < 4; pass++) {
    const int row = pass * 16 + row16;
    const int q = q0 + row;
    float acc[8];
    if (q >= vl) {
#pragma unroll
      for (int j = 0; j < 8; j++) acc[j] = mv[j];
    } else {
#pragma unroll
      for (int j = 0; j < 8; j++) acc[j] = 0.f;
#pragma unroll
      for (int sg = 0; sg < S; sg++) {
        f16x8_t v = *(const f16x8_t*)(Po + ((size_t)(sg * Bn + b) * Qn + q) * Dn + d8);
#pragma unroll
        for (int j = 0; j < 8; j++) acc[j] += (float)v[j];
      }
      const float li = linv[row];
#pragma unroll
      for (int j = 0; j < 8; j++) acc[j] *= li;
    }
    float4 o0 = make_float4(acc[0], acc[1], acc[2], acc[3]);
    float4 o1 = make_float4(acc[4], acc[5], acc[6], acc[7]);
    float* op = Out + ((size_t)b * Qn + q) * Dn + d8;
    *(float4*)op = o0;
    *(float4*)(op + 4) = o1;
  }
}

// ---------------- flash_sp: single-pass fallback (R10, proven passing) ----

__global__ void __launch_bounds__(256, 2) flash_sp(
    const f16* __restrict__ Qh, const f16* __restrict__ Kh,
    const f16* __restrict__ Vt, const int* __restrict__ vlp,
    const float* __restrict__ sv, float* __restrict__ Out) {
  const int b = blockIdx.x;
  const int qt = blockIdx.y;
  const int q0 = qt << 7;
  const int vl = load_vl(vlp, b);
  const int tid = threadIdx.x;

  if (q0 >= vl) {
    const float invK = 1.0f / (float)Kn;
    const int row = tid >> 1, h = tid & 1;
    const float4* svp = (const float4*)(sv + b * Dn + h * 64);
    float4* op = (float4*)(Out + ((size_t)b * Qn + q0 + row) * Dn + h * 64);
#pragma unroll
    for (int i = 0; i < 16; i++) {
      float4 s4 = svp[i];
      op[i] = make_float4(s4.x * invK, s4.y * invK, s4.z * invK, s4.w * invK);
    }
    return;
  }

  __shared__ __align__(16) f16 Ks[2][64 * 128];
  __shared__ __align__(16) f16 Vs[2][128 * 64];

  const int wave = tid >> 6, lane = tid & 63;
  const int H = lane >> 5, l5 = lane & 31;
  const int qbase = q0 + wave * 32;
  const bool wact = qbase < vl;
  const int q_lane = qbase + l5;
  const float sc = (q_lane >= vl) ? 0.f : SCALE;

  const int krow = (l5 & 0x13) | ((l5 & 4) << 1) | ((l5 & 8) >> 1);
  const int krow7 = krow & 7;

  f16x8_t qf[8];
  if (wact) {
    const f16* qp = Qh + ((size_t)b * Qn + q_lane) * Dn + 8 * H;
#pragma unroll
    for (int s = 0; s < 8; s++) qf[s] = *(const f16x8_t*)(qp + 16 * s);
  }

  f32x16_t O[4];
#pragma unroll
  for (int i = 0; i < 4; i++) O[i] = (f32x16_t)(0.f);
  float l_lane = 0.f;

  const char* KgT = (const char*)Kh + ((size_t)b * Kn << 8);
  const char* VgT = (const char*)Vt + ((size_t)(b * (Kn / 64)) << 14);

  {
    const char* kg = KgT + wave * 4096 + lane * 16;
    const char* vg = VgT + wave * 4096 + lane * 16;
    f16* kl = Ks[0] + wave * 2048;
    f16* vli = Vs[0] + wave * 2048;
#pragma unroll
    for (int i = 0; i < 4; i++) {
      g2l16(kg + i * 1024, kl + i * 512);
      g2l16(vg + i * 1024, vli + i * 512);
    }
  }
  __syncthreads();

  int buf = 0;
  for (int sl = 0; sl < 32; sl++) {
    if (sl < 31) {
      const char* kg = KgT + (size_t)(sl + 1) * 16384 + wave * 4096 + lane * 16;
      const char* vg = VgT + (size_t)(sl + 1) * 16384 + wave * 4096 + lane * 16;
      f16* kl = Ks[buf ^ 1] + wave * 2048;
      f16* vli = Vs[buf ^ 1] + wave * 2048;
#pragma unroll
      for (int i = 0; i < 4; i++) {
        g2l16(kg + i * 1024, kl + i * 512);
        g2l16(vg + i * 1024, vli + i * 512);
      }
    }

    if (wact) {
#pragma unroll
      for (int sub = 0; sub < 2; sub++) {
        f32x16_t T = (f32x16_t)(0.f);
        const f16* krp = Ks[buf] + ((sub * 32 + krow) << 7);
#pragma unroll
        for (int s = 0; s < 8; s++) {
          const int G = 2 * s + H;
          const int gs = (G & 8) | ((G & 7) ^ krow7);
          f16x8_t kf = *(const f16x8_t*)(krp + (gs << 3));
          T = __builtin_amdgcn_mfma_f32_32x32x16_f16(kf, qf[s], T, 0, 0, 0);
        }
        f16x8_t pf0, pf1;
        float ls = 0.f;
#pragma unroll
        for (int r = 0; r < 8; r++) {
          float p = __expf(T[r] * sc);
          ls += p;
          pf0[r] = (f16)p;
        }
#pragma unroll
        for (int r = 8; r < 16; r++) {
          float p = __expf(T[r] * sc);
          ls += p;
          pf1[r - 8] = (f16)p;
        }
        l_lane += ls;
#pragma unroll
        for (int dt = 0; dt < 4; dt++) {
          const f16* vrp = Vs[buf] + ((dt * 32 + l5) << 6);
          const int G0 = sub * 4 + H, G1 = sub * 4 + 2 + H;
          const int gs0 = G0 ^ (l5 & 7);
          const int gs1 = G1 ^ (l5 & 7);
          f16x8_t vf0 = *(const f16x8_t*)(vrp + (gs0 << 3));
          f16x8_t vf1 = *(const f16x8_t*)(vrp + (gs1 << 3));
          O[dt] = __builtin_amdgcn_mfma_f32_32x32x16_f16(pf0, vf0, O[dt], 0, 0, 0);
          O[dt] = __builtin_amdgcn_mfma_f32_32x32x16_f16(pf1, vf1, O[dt], 0, 0, 0);
        }
      }
    }
    __syncthreads();
    buf ^= 1;
  }

  float* op = Out + ((size_t)b * Qn + qbase) * Dn;
  if (wact) {
    float ll = l_lane + __shfl_xor(l_lane, 32);
    float inv[16];
#pragma unroll
    for (int r = 0; r < 16; r++) {
      const int qrow = (r & 3) + 8 * (r >> 2) + 4 * H;
      inv[r] = 1.0f / __shfl(ll, qrow);
    }
#pragma unroll
    for (int dt = 0; dt < 4; dt++) {
#pragma unroll
      for (int r = 0; r < 16; r++) {
        const int qrow = (r & 3) + 8 * (r >> 2) + 4 * H;
        op[(size_t)qrow * Dn + dt * 32 + l5] = O[dt][r] * inv[r];
      }
    }
  } else {
    const float invK = 1.0f / (float)Kn;
#pragma unroll
    for (int dt = 0; dt < 4; dt++) {
      const float svv = sv[b * Dn + dt * 32 + l5] * invK;
#pragma unroll
      for (int r = 0; r < 16; r++) {
        const int qrow = (r & 3) + 8 * (r >> 2) + 4 * H;
        op[(size_t)qrow * Dn + dt * 32 + l5] = svv;
      }
    }
  }
}

// ---------------- launch ----------------

extern "C" void kernel_launch(void* const* d_in, const int* in_sizes, int n_in,
                              void* d_out, int out_size, void* d_ws, size_t ws_size,
                              hipStream_t stream) {
  const float* Qg = (const float*)d_in[0];
  const float* Kg = (const float*)d_in[1];
  const float* Vg = (const float*)d_in[2];
  const int* vl = (const int*)d_in[3];
  float* Out = (float*)d_out;

  char* ws = (char*)d_ws;
  const size_t kv = (size_t)Bn * Kn * Dn * 2;  // 8.39 MB each
  float* sumV = (float*)ws;                    // 8 KB
  f16* Kh = (f16*)(ws + 8192);
  f16* Vt = (f16*)(ws + 8192 + kv);
  f16* Qh = (f16*)(ws + 8192 + 2 * kv);

  const size_t plane = (size_t)Bn * Qn * Dn * 2;  // 8.39 MB
  const size_t lplane = (size_t)Bn * Qn * 4;      // 128 KB
  const size_t base = 8192 + 3 * kv;              // ~25.2 MB
  const size_t need4 = base + 4 * (plane + lplane);  // ~59.3 MB

  hipMemsetAsync(sumV, 0, Bn * Dn * sizeof(float), stream);

  prep_kernel<<<dim3(32, 4, Bn), dim3(32, 8), 0, stream>>>(
      Qg, Kg, Vg, Qh, Kh, Vt, sumV);

  if (ws_size >= need4) {
    // primary: SEG=4, balanced grid (qt, seg, b), counted-vmcnt sync
    f16* Po = (f16*)(ws + base);
    float* Lb = (float*)(ws + base + 4 * plane);
    flash4<<<dim3(16, 4, Bn), 256, 0, stream>>>(Qh, Kh, Vt, vl, Po, Lb);
    combine_kernel<4><<<dim3(Qn / 64, Bn), 256, 0, stream>>>(Po, Lb, sumV, vl, Out);
  } else {
    // fallback: R10 single-pass (proven passing)
    flash_sp<<<dim3(Bn, 16), 256, 0, stream>>>(Qh, Kh, Vt, vl, sumV, Out);
  }
}